// Round 1
// baseline (147.011 us; speedup 1.0000x reference)
//
#include <hip/hip_runtime.h>

#define NQ 10
#define NP 81
#define TT 8

__device__ __forceinline__ float sigm(float z) {
    z = fminf(fmaxf(z, -30.f), 30.f);
    return 1.f / (1.f + __expf(-z));
}
__device__ __forceinline__ float tanh_(float z) {
    z = fminf(fmaxf(z, -15.f), 15.f);
    float e = __expf(2.f * z);
    return (e - 1.f) / (e + 1.f);
}

// feats (30 regs) @ R_c (30x10, row-major) -> g_s slot
__device__ __forceinline__ void matvec30(const float* __restrict__ Rb,
                                         const float ft[30],
                                         float (*gdst)[64], int lane) {
#pragma unroll
    for (int k = 0; k < NQ; ++k) {
        float acc = 0.f;
#pragma unroll
        for (int f = 0; f < 30; ++f) acc = fmaf(ft[f], Rb[f * 10 + k], acc);
        gdst[k][lane] = acc;
    }
}

// One block = 64 batch elements (lane = batch), 4 waves split the work.
// All six circuits evaluated in closed form (exact algebra, see derivations):
//  forget/memory: 2-qubit CZ blocks;  input/output: CNOT chain = prefix-XOR
//  transfer matrices;  candidate: CZ graph-state formula;  temporal: ZZ-chain
//  diagonal entangler. circ_output features are the constant (0,1,0)x10.
__global__ __launch_bounds__(256) void qlstm_kernel(
    const float* __restrict__ x, const float* __restrict__ Wx,
    const float* __restrict__ Wh, const float* __restrict__ bias,
    const float* __restrict__ R, float* __restrict__ out) {
    __shared__ float p_s[NP][64];
    __shared__ float h_s[NQ][64];
    __shared__ float c_s[NQ][64];
    __shared__ float g_s[5][NQ][64];  // 0=f 1=i 2=g(cand) 3=mq 4=tm

    const int lane = threadIdx.x & 63;
    const int wave = __builtin_amdgcn_readfirstlane((int)(threadIdx.x >> 6));
    const int b = blockIdx.x * 64 + lane;

    if (wave == 0) {
#pragma unroll
        for (int k = 0; k < NQ; ++k) { h_s[k][lane] = 0.f; c_s[k][lane] = 0.f; }
    }

    // constant o gate: sigmoid( sum_q R2[3q+1, k] )  (circ_output feats = (0,1,0)^10)
    float o_g[NQ];
#pragma unroll
    for (int k = 0; k < NQ; ++k) {
        float s = 0.f;
#pragma unroll
        for (int q = 0; q < NQ; ++q) s += R[2 * 300 + (3 * q + 1) * 10 + k];
        o_g[k] = sigm(s);
    }
    __syncthreads();

    for (int t = 0; t < TT; ++t) {
        // ---- P1: p = x_t @ Wx + h @ Wh + bias  (waves split the 81 columns)
        float xr[NQ], hr[NQ];
#pragma unroll
        for (int k = 0; k < NQ; ++k) xr[k] = x[(b * TT + t) * NQ + k];
#pragma unroll
        for (int k = 0; k < NQ; ++k) hr[k] = h_s[k][lane];
        for (int j = wave; j < NP; j += 4) {
            float acc = bias[j];
#pragma unroll
            for (int k = 0; k < NQ; ++k)
                acc = fmaf(xr[k], Wx[k * NP + j], fmaf(hr[k], Wh[k * NP + j], acc));
            p_s[j][lane] = acc;
        }
        __syncthreads();

        // ---- P2: circuits (closed form), one circuit group per wave
        if (wave == 0) {
            // ---- forget: RY layer, CZ(2k,2k+1), T layer -------------------
            float sa[NQ], ca[NQ], ft[30];
#pragma unroll
            for (int q = 0; q < NQ; ++q) __sincosf(p_s[q][lane], &sa[q], &ca[q]);
            const float r2 = 0.70710678118654752f;
#pragma unroll
            for (int k5 = 0; k5 < 5; ++k5) {
                int q = 2 * k5, q1 = q + 1;
                ft[3 * q] = -sa[q];
                float v = -r2 * ca[q] * sa[q1];
                ft[3 * q + 1] = v; ft[3 * q + 2] = v;
                ft[3 * q1] = -sa[q1];
                float v2 = -r2 * ca[q1] * sa[q];
                ft[3 * q1 + 1] = v2; ft[3 * q1 + 2] = v2;
            }
            matvec30(R + 0 * 300, ft, g_s[0], lane);

            // ---- memory: same but no T gates -----------------------------
#pragma unroll
            for (int q = 0; q < NQ; ++q) __sincosf(p_s[70 + q][lane], &sa[q], &ca[q]);
#pragma unroll
            for (int k5 = 0; k5 < 5; ++k5) {
                int q = 2 * k5, q1 = q + 1;
                ft[3 * q] = -sa[q];
                ft[3 * q + 1] = -ca[q] * sa[q1];
                ft[3 * q + 2] = 0.f;
                ft[3 * q1] = -sa[q1];
                ft[3 * q1 + 1] = -ca[q1] * sa[q];
                ft[3 * q1 + 2] = 0.f;
            }
            matvec30(R + 4 * 300, ft, g_s[3], lane);
        } else if (wave == 1) {
            // ---- input: RY,RZ per qubit + CNOT chain ---------------------
            float sa[NQ], ca[NQ], sb[NQ], cb[NQ], ft[30];
#pragma unroll
            for (int q = 0; q < NQ; ++q) __sincosf(p_s[10 + 2 * q][lane], &sa[q], &ca[q]);
#pragma unroll
            for (int q = 0; q < NQ; ++q) __sincosf(p_s[11 + 2 * q][lane], &sb[q], &cb[q]);
            float xx[NQ], uu[NQ];
#pragma unroll
            for (int q = 0; q < NQ; ++q) { xx[q] = ca[q] * cb[q]; uu[q] = ca[q] * sb[q]; }
            float Zprev = 1.f;
#pragma unroll
            for (int q = 0; q < NQ; ++q) {
                float zq = Zprev * (-sa[q]);
                float xn = (q < 9) ? xx[q + 1] : 1.f;
                ft[3 * q] = zq;
                ft[3 * q + 1] = xx[q] * xn;
                ft[3 * q + 2] = uu[q] * Zprev * xn;
                Zprev = zq;
            }
            matvec30(R + 1 * 300, ft, g_s[1], lane);
        } else if (wave == 2) {
            // ---- candidate: H -> |0..0>, RZ RY RZ, CZ graph --------------
            // CAND_CZ (np.random.seed(0), thresh 0.7): (0,2)(0,8)(0,9)(1,3)(1,6)
            // (2,3)(2,4)(2,5)(2,6)(2,7)(2,9)(3,7)(4,6)(5,9)
            float sb[NQ], cb[NQ], sc[NQ], cc[NQ], ft[30];
#pragma unroll
            for (int q = 0; q < NQ; ++q) __sincosf(p_s[41 + 3 * q][lane], &sb[q], &cb[q]);
#pragma unroll
            for (int q = 0; q < NQ; ++q) __sincosf(p_s[42 + 3 * q][lane], &sc[q], &cc[q]);
            float P[NQ];
            P[0] = cb[2] * cb[8] * cb[9];
            P[1] = cb[3] * cb[6];
            P[2] = cb[0] * cb[3] * cb[4] * cb[5] * cb[6] * cb[7] * cb[9];
            P[3] = cb[1] * cb[2] * cb[7];
            P[4] = cb[2] * cb[6];
            P[5] = cb[2] * cb[9];
            P[6] = cb[1] * cb[2] * cb[4];
            P[7] = cb[2] * cb[3];
            P[8] = cb[0];
            P[9] = cb[0] * cb[2] * cb[5];
#pragma unroll
            for (int q = 0; q < NQ; ++q) {
                ft[3 * q] = cb[q];
                float m = sb[q] * P[q];
                ft[3 * q + 1] = m * cc[q];
                ft[3 * q + 2] = m * sc[q];
            }
            matvec30(R + 3 * 300, ft, g_s[2], lane);
        } else {
            // ---- temporal: |0>|+>^9, RZ(0.1t) RX(0.05t), ZZ chain(0.2t) --
            float tt = p_s[80][lane];
            float s1, c1, s2, c2, s3, c3, s4, c4, s6, c6, s8, c8, ft[30];
            __sincosf(0.025f * tt, &s1, &c1);
            __sincosf(0.050f * tt, &s2, &c2);
            __sincosf(0.075f * tt, &s3, &c3);
            __sincosf(0.100f * tt, &s4, &c4);
            __sincosf(0.150f * tt, &s6, &c6);
            __sincosf(0.200f * tt, &s8, &c8);
            (void)s1; (void)c1; (void)s3; (void)c3; (void)s4;
            float z0 = c2;                       // qubit0 <Z>
            float zs = 0.5f * (c2 - c6);         // qubits 1..9 <Z>
            float mre = 0.5f * c4;               // m = conj(v0)v1, qubits 1..9
            float mim = 0.25f * (s2 + s6);
            float E0re = c8, E0im = z0 * s8;     // E = cos(0.2t)+i*z*sin(0.2t)
            float Esre = c8, Esim = zs * s8;
            // cr0 = (-i*0.5*sin(0.05t)) * Es
            float cr0re = 0.5f * s2 * Esim;
            float cr0im = -0.5f * s2 * Esre;
            float EEre = Esre * Esre - Esim * Esim, EEim = 2.f * Esre * Esim;
            float EOre = E0re * Esre - E0im * Esim, EOim = E0re * Esim + E0im * Esre;
            float cr1re = mre * EOre - mim * EOim, cr1im = mre * EOim + mim * EOre;
            float crmre = mre * EEre - mim * EEim, crmim = mre * EEim + mim * EEre;
            float cr9re = mre * Esre - mim * Esim, cr9im = mre * Esim + mim * Esre;
            ft[0] = z0; ft[1] = 2.f * cr0re; ft[2] = 2.f * cr0im;
            ft[3] = zs; ft[4] = 2.f * cr1re; ft[5] = 2.f * cr1im;
#pragma unroll
            for (int q = 2; q <= 8; ++q) {
                ft[3 * q] = zs; ft[3 * q + 1] = 2.f * crmre; ft[3 * q + 2] = 2.f * crmim;
            }
            ft[27] = zs; ft[28] = 2.f * cr9re; ft[29] = 2.f * cr9im;
            matvec30(R + 5 * 300, ft, g_s[4], lane);
        }
        __syncthreads();

        // ---- P3: LSTM cell update (waves split k)
        for (int k = wave; k < NQ; k += 4) {
            float f = sigm(g_s[0][k][lane]);
            float ii = sigm(g_s[1][k][lane]);
            float g = tanh_(g_s[2][k][lane]);
            float mq = sigm(g_s[3][k][lane]);
            float tm = tanh_(g_s[4][k][lane]);
            float cn = (f * c_s[k][lane] + ii * g) * mq;
            float hn = o_g[k] * tanh_(cn) + 0.1f * tm;
            c_s[k][lane] = cn;
            h_s[k][lane] = hn;
            out[(b * TT + t) * NQ + k] = hn;
        }
        __syncthreads();
    }
}

extern "C" void kernel_launch(void* const* d_in, const int* in_sizes, int n_in,
                              void* d_out, int out_size, void* d_ws, size_t ws_size,
                              hipStream_t stream) {
    const float* x = (const float*)d_in[0];     // (2048, 8, 10) f32
    const float* Wx = (const float*)d_in[1];    // (10, 81)
    const float* Wh = (const float*)d_in[2];    // (10, 81)
    const float* bias = (const float*)d_in[3];  // (81,)
    const float* R = (const float*)d_in[4];     // (6, 30, 10)
    float* out = (float*)d_out;                 // (2048, 8, 10) f32

    qlstm_kernel<<<dim3(32), dim3(256), 0, stream>>>(x, Wx, Wh, bias, R, out);
}

// Round 2
// 78.953 us; speedup vs baseline: 1.8620x; 1.8620x over previous
//
#include <hip/hip_runtime.h>

#define NQ 10
#define NP 81
#define TT 8

__device__ __forceinline__ float sigm(float z) {
    z = fminf(fmaxf(z, -30.f), 30.f);
    return 1.f / (1.f + __expf(-z));
}
__device__ __forceinline__ float tanh_(float z) {
    z = fminf(fmaxf(z, -15.f), 15.f);
    float e = __expf(2.f * z);
    return (e - 1.f) / (e + 1.f);
}

// 256 blocks x 256 threads; block handles 8 batch elements through the full
// T=8 scan. Phases per timestep (4 barriers):
//   P1: p[8][81] = x_t@Wx + h@Wh + b   (thread=(batch-half, col j); W cols in regs)
//   A : closed-form circuit features -> ft_s[f][g*5+circ] (1 circuit/wave)
//   B : 400 dot-30 products (thread=job, R rows in regs)
//   C : LSTM cell update (80 threads)
__global__ __launch_bounds__(256) void qlstm_kernel(
    const float* __restrict__ x, const float* __restrict__ Wx,
    const float* __restrict__ Wh, const float* __restrict__ bias,
    const float* __restrict__ R, float* __restrict__ out) {

    __shared__ float x_s[8 * 8 * 12];   // [g][t][k pad 12] (48B rows, b128-able)
    __shared__ float h_s[8 * 12];       // [g][k pad 12]
    __shared__ float c_s[8 * 10];
    __shared__ float p_s[8 * NP];       // [g][j]
    __shared__ float ft_s[30 * 40];     // [f][g*5+circ]  (conflict-free both ways)
    __shared__ float g_s[8 * 5 * 10];   // [g][gate][k], flat addr == job id

    const int tid = threadIdx.x;
    const int bbase = blockIdx.x * 8;

    // ---- one-time: stage x (contiguous 640 floats for this block's 8 batches)
    for (int i = tid; i < 640; i += 256) {
        int g = i / 80, r = i - g * 80;
        int t = r / 10, k = r - t * 10;
        x_s[g * 96 + t * 12 + k] = x[(size_t)bbase * 80 + i];
    }
    if (tid < 96) h_s[tid] = 0.f;
    if (tid < 80) c_s[tid] = 0.f;

    // ---- P1 preload: thread -> (batch-half gh, column j1); W columns in regs
    const int j1 = tid & 127;
    const int g0 = (tid >> 7) * 4;
    const bool p1act = (j1 < NP);
    float wx[NQ], wh[NQ], bj = 0.f;
    if (p1act) {
#pragma unroll
        for (int k = 0; k < NQ; ++k) { wx[k] = Wx[k * NP + j1]; wh[k] = Wh[k * NP + j1]; }
        bj = bias[j1];
    }

    // ---- stage B preload: jobs tid and tid+256 (job = g*50 + gate*10 + k)
    // gate order: 0=f(R0) 1=i(R1) 2=cand(R3) 3=mq(R4) 4=tm(R5)
    const int gB1 = tid / 50, remB1 = tid - gB1 * 50;
    const int gt1 = remB1 / 10, k1 = remB1 - gt1 * 10;
    const int gR1 = gt1 + (gt1 >= 2 ? 1 : 0);
    float r1[30];
#pragma unroll
    for (int f = 0; f < 30; ++f) r1[f] = R[gR1 * 300 + f * 10 + k1];
    const bool hasj2 = (tid < 144);
    const int jb2 = tid + 256;
    const int gB2 = jb2 / 50, remB2 = jb2 - gB2 * 50;
    const int gt2 = remB2 / 10, k2 = remB2 - gt2 * 10;
    const int gR2 = gt2 + (gt2 >= 2 ? 1 : 0);
    float r2[30];
    if (hasj2) {
#pragma unroll
        for (int f = 0; f < 30; ++f) r2[f] = R[gR2 * 300 + f * 10 + k2];
    }

    // ---- stage C preload: constant o gate (circ_output feats = (0,1,0)^10)
    const bool hasC = (tid < 80);
    const int gC = tid / 10, kC = tid - gC * 10;
    float o_val = 0.f;
    if (hasC) {
        float s = 0.f;
#pragma unroll
        for (int q = 0; q < NQ; ++q) s += R[600 + (3 * q + 1) * 10 + kC];
        o_val = sigm(s);
    }

    const int wv = tid >> 6, ln = tid & 63;
    __syncthreads();

    for (int t = 0; t < TT; ++t) {
        // ================= P1 =================
        if (p1act) {
            float acc[4];
#pragma unroll
            for (int i = 0; i < 4; ++i) acc[i] = bj;
#pragma unroll
            for (int i = 0; i < 4; ++i) {
                const float* xr = &x_s[(g0 + i) * 96 + t * 12];
                const float* hr = &h_s[(g0 + i) * 12];
#pragma unroll
                for (int k = 0; k < NQ; ++k)
                    acc[i] = fmaf(xr[k], wx[k], fmaf(hr[k], wh[k], acc[i]));
            }
#pragma unroll
            for (int i = 0; i < 4; ++i) p_s[(g0 + i) * NP + j1] = acc[i];
        }
        __syncthreads();

        // ================= stage A: features =================
        if (wv == 0 && ln < 8) {
            // forget (circ 0): RY, CZ(2m,2m+1), T
            const int g = ln;
            const float* pp = &p_s[g * NP];
            float sa[NQ], ca[NQ], ftl[30];
#pragma unroll
            for (int q = 0; q < NQ; ++q) __sincosf(pp[q], &sa[q], &ca[q]);
            const float r2c = 0.70710678118654752f;
#pragma unroll
            for (int m = 0; m < 5; ++m) {
                int q = 2 * m, q1 = q + 1;
                ftl[3 * q] = -sa[q];
                float v = -r2c * ca[q] * sa[q1];
                ftl[3 * q + 1] = v; ftl[3 * q + 2] = v;
                ftl[3 * q1] = -sa[q1];
                float v2 = -r2c * ca[q1] * sa[q];
                ftl[3 * q1 + 1] = v2; ftl[3 * q1 + 2] = v2;
            }
#pragma unroll
            for (int f = 0; f < 30; ++f) ft_s[f * 40 + g * 5 + 0] = ftl[f];
        } else if (wv == 1 && ln < 8) {
            // input (circ 1): RY,RZ + CNOT chain (prefix-XOR transfer matrices)
            const int g = ln;
            const float* pp = &p_s[g * NP];
            float sa[NQ], ca[NQ], sb[NQ], cb[NQ], ftl[30];
#pragma unroll
            for (int q = 0; q < NQ; ++q) __sincosf(pp[10 + 2 * q], &sa[q], &ca[q]);
#pragma unroll
            for (int q = 0; q < NQ; ++q) __sincosf(pp[11 + 2 * q], &sb[q], &cb[q]);
            float xx[NQ], uu[NQ];
#pragma unroll
            for (int q = 0; q < NQ; ++q) { xx[q] = ca[q] * cb[q]; uu[q] = ca[q] * sb[q]; }
            float Zprev = 1.f;
#pragma unroll
            for (int q = 0; q < NQ; ++q) {
                float zq = Zprev * (-sa[q]);
                float xn = (q < 9) ? xx[q + 1] : 1.f;
                ftl[3 * q] = zq;
                ftl[3 * q + 1] = xx[q] * xn;
                ftl[3 * q + 2] = uu[q] * Zprev * xn;
                Zprev = zq;
            }
#pragma unroll
            for (int f = 0; f < 30; ++f) ft_s[f * 40 + g * 5 + 1] = ftl[f];
        } else if (wv == 2 && ln < 8) {
            // candidate (circ 2): H->|0..0>, RZ RY RZ, CZ graph
            // CAND_CZ: (0,2)(0,8)(0,9)(1,3)(1,6)(2,3)(2,4)(2,5)(2,6)(2,7)(2,9)
            //          (3,7)(4,6)(5,9)
            const int g = ln;
            const float* pp = &p_s[g * NP];
            float sb[NQ], cb[NQ], sc[NQ], cc[NQ], ftl[30];
#pragma unroll
            for (int q = 0; q < NQ; ++q) __sincosf(pp[41 + 3 * q], &sb[q], &cb[q]);
#pragma unroll
            for (int q = 0; q < NQ; ++q) __sincosf(pp[42 + 3 * q], &sc[q], &cc[q]);
            float P[NQ];
            P[0] = cb[2] * cb[8] * cb[9];
            P[1] = cb[3] * cb[6];
            P[2] = cb[0] * cb[3] * cb[4] * cb[5] * cb[6] * cb[7] * cb[9];
            P[3] = cb[1] * cb[2] * cb[7];
            P[4] = cb[2] * cb[6];
            P[5] = cb[2] * cb[9];
            P[6] = cb[1] * cb[2] * cb[4];
            P[7] = cb[2] * cb[3];
            P[8] = cb[0];
            P[9] = cb[0] * cb[2] * cb[5];
#pragma unroll
            for (int q = 0; q < NQ; ++q) {
                ftl[3 * q] = cb[q];
                float m = sb[q] * P[q];
                ftl[3 * q + 1] = m * cc[q];
                ftl[3 * q + 2] = m * sc[q];
            }
#pragma unroll
            for (int f = 0; f < 30; ++f) ft_s[f * 40 + g * 5 + 2] = ftl[f];
        } else if (wv == 3 && ln < 16) {
            if (ln < 8) {
                // temporal (circ 4): |0>|+>^9, RZ(0.1t) RX(0.05t), ZZ chain(0.2t)
                const int g = ln;
                float tt = p_s[g * NP + 80];
                float s2, c2, s4, c4, s6, c6, s8, c8, ftl[30];
                __sincosf(0.050f * tt, &s2, &c2);
                __sincosf(0.100f * tt, &s4, &c4);
                __sincosf(0.150f * tt, &s6, &c6);
                __sincosf(0.200f * tt, &s8, &c8);
                (void)s4;
                float z0 = c2;
                float zs = 0.5f * (c2 - c6);
                float mre = 0.5f * c4;
                float mim = 0.25f * (s2 + s6);
                float E0re = c8, E0im = z0 * s8;
                float Esre = c8, Esim = zs * s8;
                float cr0re = 0.5f * s2 * Esim;
                float cr0im = -0.5f * s2 * Esre;
                float EEre = Esre * Esre - Esim * Esim, EEim = 2.f * Esre * Esim;
                float EOre = E0re * Esre - E0im * Esim, EOim = E0re * Esim + E0im * Esre;
                float cr1re = mre * EOre - mim * EOim, cr1im = mre * EOim + mim * EOre;
                float crmre = mre * EEre - mim * EEim, crmim = mre * EEim + mim * EEre;
                float cr9re = mre * Esre - mim * Esim, cr9im = mre * Esim + mim * Esre;
                ftl[0] = z0; ftl[1] = 2.f * cr0re; ftl[2] = 2.f * cr0im;
                ftl[3] = zs; ftl[4] = 2.f * cr1re; ftl[5] = 2.f * cr1im;
#pragma unroll
                for (int q = 2; q <= 8; ++q) {
                    ftl[3 * q] = zs; ftl[3 * q + 1] = 2.f * crmre; ftl[3 * q + 2] = 2.f * crmim;
                }
                ftl[27] = zs; ftl[28] = 2.f * cr9re; ftl[29] = 2.f * cr9im;
#pragma unroll
                for (int f = 0; f < 30; ++f) ft_s[f * 40 + g * 5 + 4] = ftl[f];
            } else {
                // memory (circ 3): RY, CZ(2m,2m+1)
                const int g = ln - 8;
                const float* pp = &p_s[g * NP];
                float sa[NQ], ca[NQ], ftl[30];
#pragma unroll
                for (int q = 0; q < NQ; ++q) __sincosf(pp[70 + q], &sa[q], &ca[q]);
#pragma unroll
                for (int m = 0; m < 5; ++m) {
                    int q = 2 * m, q1 = q + 1;
                    ftl[3 * q] = -sa[q];
                    ftl[3 * q + 1] = -ca[q] * sa[q1];
                    ftl[3 * q + 2] = 0.f;
                    ftl[3 * q1] = -sa[q1];
                    ftl[3 * q1 + 1] = -ca[q1] * sa[q];
                    ftl[3 * q1 + 2] = 0.f;
                }
#pragma unroll
                for (int f = 0; f < 30; ++f) ft_s[f * 40 + g * 5 + 3] = ftl[f];
            }
        }
        __syncthreads();

        // ================= stage B: 400 dot-30 =================
        {
            const int base1 = gB1 * 5 + gt1;
            float acc = 0.f;
#pragma unroll
            for (int f = 0; f < 30; ++f) acc = fmaf(ft_s[f * 40 + base1], r1[f], acc);
            g_s[tid] = acc;  // flat job id == g*50+gate*10+k
            if (hasj2) {
                const int base2 = gB2 * 5 + gt2;
                float acc2 = 0.f;
#pragma unroll
                for (int f = 0; f < 30; ++f) acc2 = fmaf(ft_s[f * 40 + base2], r2[f], acc2);
                g_s[jb2] = acc2;
            }
        }
        __syncthreads();

        // ================= stage C: cell update =================
        if (hasC) {
            float f = sigm(g_s[gC * 50 + 0 * 10 + kC]);
            float ii = sigm(g_s[gC * 50 + 1 * 10 + kC]);
            float gg = tanh_(g_s[gC * 50 + 2 * 10 + kC]);
            float mq = sigm(g_s[gC * 50 + 3 * 10 + kC]);
            float tm = tanh_(g_s[gC * 50 + 4 * 10 + kC]);
            float cn = (f * c_s[gC * 10 + kC] + ii * gg) * mq;
            float hn = o_val * tanh_(cn) + 0.1f * tm;
            c_s[gC * 10 + kC] = cn;
            h_s[gC * 12 + kC] = hn;
            out[(size_t)(bbase + gC) * 80 + t * 10 + kC] = hn;
        }
        __syncthreads();
    }
}

extern "C" void kernel_launch(void* const* d_in, const int* in_sizes, int n_in,
                              void* d_out, int out_size, void* d_ws, size_t ws_size,
                              hipStream_t stream) {
    const float* x = (const float*)d_in[0];     // (2048, 8, 10) f32
    const float* Wx = (const float*)d_in[1];    // (10, 81)
    const float* Wh = (const float*)d_in[2];    // (10, 81)
    const float* bias = (const float*)d_in[3];  // (81,)
    const float* R = (const float*)d_in[4];     // (6, 30, 10)
    float* out = (float*)d_out;                 // (2048, 8, 10) f32

    qlstm_kernel<<<dim3(256), dim3(256), 0, stream>>>(x, Wx, Wh, bias, R, out);
}